// Round 1
// baseline (844.657 us; speedup 1.0000x reference)
//
#include <hip/hip_runtime.h>
#include <math.h>

#define B_ 2
#define C_ 36
#define H_ 512
#define W_ 512
#define K_ 9
#define HW_ (H_ * W_)

// ---------------------------------------------------------------------------
// Transpose features [B,C,H,W] -> [B,H,W,C] so that one sample position's
// 36 channels (and the adjacent column's 36 channels) are one contiguous
// 288-byte run -> float4 gathers with high cache-line utilization.
// ---------------------------------------------------------------------------
__global__ __launch_bounds__(256) void transpose_kernel(const float* __restrict__ in,
                                                        float* __restrict__ out) {
  __shared__ float tile[64][37];  // +1 pad: stride 37 mod 32 = 5 -> conflict-free
  int blk = blockIdx.x;           // ((b*H + h)*8 + wt)
  int wt = blk & 7;
  int h = (blk >> 3) & (H_ - 1);
  int b = blk >> 12;
  int w0 = wt << 6;
  int tid = threadIdx.x;
  const float* src = in + ((size_t)b * C_) * HW_ + (size_t)h * W_ + w0;
#pragma unroll
  for (int it = 0; it < 9; ++it) {  // 36 ch * 64 w = 2304 elems / 256 thr
    int idx = it * 256 + tid;
    int c = idx >> 6;
    int wl = idx & 63;
    tile[wl][c] = src[(size_t)c * HW_ + wl];  // coalesced along w
  }
  __syncthreads();
  float* dst = out + (((size_t)b * H_ + h) * W_ + w0) * C_;
#pragma unroll
  for (int it = 0; it < 9; ++it) {
    int idx = it * 256 + tid;
    int wl = idx / 36;
    int c = idx - wl * 36;
    dst[idx] = tile[wl][c];  // fully coalesced contiguous store
  }
}

// ---------------------------------------------------------------------------
// Main kernel: one thread per output pixel.
// TRANS=true  : feat is [B,H,W,C] (transposed scratch) -> float4 gathers
// TRANS=false : feat is [B,C,H,W] (original)           -> scalar gathers
// ---------------------------------------------------------------------------
template <bool TRANS>
__global__ __launch_bounds__(256) void eval_kernel(const float* __restrict__ feat,
                                                   const float* __restrict__ offx,
                                                   const float* __restrict__ offy,
                                                   const float* __restrict__ lxp,
                                                   const float* __restrict__ lyp,
                                                   float* __restrict__ out) {
  int p = blockIdx.x * 256 + threadIdx.x;  // 0 .. B*H*W
  int ph = p & (HW_ - 1);
  int b = p >> 18;  // HW_ = 2^18

  // center-pixel features, all 36 channels
  float F[C_];
  if constexpr (TRANS) {
    const float4* fb = reinterpret_cast<const float4*>(feat + (size_t)p * C_);
#pragma unroll
    for (int q = 0; q < 9; ++q) {
      float4 v = fb[q];
      F[4 * q + 0] = v.x; F[4 * q + 1] = v.y; F[4 * q + 2] = v.z; F[4 * q + 3] = v.w;
    }
  } else {
    const float* fb = feat + (size_t)b * C_ * HW_ + ph;
#pragma unroll
    for (int c = 0; c < C_; ++c) F[c] = fb[(size_t)c * HW_];
  }

  float lx = lxp[b * HW_ + ph];  // == w
  float ly = lyp[b * HW_ + ph];  // == h

  const float* oxb = offx + (size_t)b * K_ * HW_ + ph;
  const float* oyb = offy + (size_t)b * K_ * HW_ + ph;

  // online softmax state (temp-1000 logits)
  float M = -INFINITY, den = 0.f, ax = 0.f, ay = 0.f;

#pragma unroll 1
  for (int k = 0; k < K_; ++k) {
    float ox = oxb[k * HW_];
    float oy = oyb[k * HW_];
    // replicate reference fp32 chain: clip -> normalize -> denormalize
    float rx = fminf(fmaxf(lx + ox, 0.0f), 511.0f);
    float ry = fminf(fmaxf(ly + oy, 0.0f), 511.0f);
    float gx = (rx - 255.5f) / 255.5f;
    float gy = (ry - 255.5f) / 255.5f;
    float px = (gx + 1.0f) * 0.5f * 511.0f;
    float py = (gy + 1.0f) * 0.5f * 511.0f;
    // clamp corner to <=510 and fold border into weight=1 (bit-equivalent to
    // the reference's clip(x0)/clip(x0+1) because the w=0 term vanishes)
    int x0 = (int)floorf(px); x0 = (x0 > W_ - 2) ? (W_ - 2) : x0;
    int y0 = (int)floorf(py); y0 = (y0 > H_ - 2) ? (H_ - 2) : y0;
    float wx = px - (float)x0;
    float wy = py - (float)y0;
    float w00 = (1.0f - wx) * (1.0f - wy);
    float w01 = wx * (1.0f - wy);
    float w10 = (1.0f - wx) * wy;
    float w11 = wx * wy;

    float D[9] = {0.f, 0.f, 0.f, 0.f, 0.f, 0.f, 0.f, 0.f, 0.f};

    if constexpr (TRANS) {
      const float* r0 = feat + (((size_t)(b * H_ + y0)) * W_ + x0) * C_;
      const float* r1 = r0 + (size_t)W_ * C_;
#pragma unroll
      for (int q = 0; q < 9; ++q) {
        float4 a00 = *reinterpret_cast<const float4*>(r0 + 4 * q);        // col x0
        float4 a01 = *reinterpret_cast<const float4*>(r0 + C_ + 4 * q);   // col x0+1
        float4 a10 = *reinterpret_cast<const float4*>(r1 + 4 * q);
        float4 a11 = *reinterpret_cast<const float4*>(r1 + C_ + 4 * q);
        float t00[4] = {a00.x, a00.y, a00.z, a00.w};
        float t01[4] = {a01.x, a01.y, a01.z, a01.w};
        float t10[4] = {a10.x, a10.y, a10.z, a10.w};
        float t11[4] = {a11.x, a11.y, a11.z, a11.w};
#pragma unroll
        for (int j = 0; j < 4; ++j) {
          int c = 4 * q + j;
          float a = t00[j] * w00 + t01[j] * w01 + t10[j] * w10 + t11[j] * w11;
          int i = c % 12;
          int ga = c / 12;
          D[ga]     += fabsf(F[i]      - a);
          D[3 + ga] += fabsf(F[12 + i] - a);
          D[6 + ga] += fabsf(F[24 + i] - a);
        }
      }
    } else {
      const float* pl = feat + (size_t)b * C_ * HW_ + (size_t)y0 * W_ + x0;
#pragma unroll
      for (int c = 0; c < C_; ++c) {
        const float* q0 = pl + (size_t)c * HW_;
        float v00 = q0[0], v01 = q0[1];
        float v10 = q0[W_], v11 = q0[W_ + 1];
        float a = v00 * w00 + v01 * w01 + v10 * w10 + v11 * w11;
        int i = c % 12;
        int ga = c / 12;
        D[ga]     += fabsf(F[i]      - a);
        D[3 + ga] += fabsf(F[12 + i] - a);
        D[6 + ga] += fabsf(F[24 + i] - a);
      }
    }

    // strength*1000 logit; max(-D/12) == -(min D)/12 (monotone ops)
    float mn = D[0];
#pragma unroll
    for (int j = 1; j < 9; ++j) mn = fminf(mn, D[j]);
    float xk = -(mn / 12.0f) * 1000.0f;

    // online softmax update
    float nm = fmaxf(M, xk);
    float sc = expf(M - nm);   // exp(-inf)=0 on first iteration
    float ek = expf(xk - nm);
    den = den * sc + ek;
    ax = ax * sc + ox * ek;
    ay = ay * sc + oy * ek;
    M = nm;
  }

  float resx = ax / den;
  float resy = ay / den;
  float o0 = fminf(fmaxf(resx + lx, 0.0f), 511.0f) - lx;
  float o1 = fminf(fmaxf(resy + ly, 0.0f), 511.0f) - ly;
  out[p] = o0;               // ox plane
  out[B_ * HW_ + p] = o1;    // oy plane
}

extern "C" void kernel_launch(void* const* d_in, const int* in_sizes, int n_in,
                              void* d_out, int out_size, void* d_ws, size_t ws_size,
                              hipStream_t stream) {
  const float* features = (const float*)d_in[0];
  const float* offset_x = (const float*)d_in[1];
  const float* offset_y = (const float*)d_in[2];
  const float* left_x   = (const float*)d_in[3];
  const float* left_y   = (const float*)d_in[4];
  float* out = (float*)d_out;

  const int npix = B_ * HW_;             // 524288
  const size_t need = (size_t)npix * C_ * sizeof(float);  // 75.5 MB

  if (ws_size >= need) {
    float* featT = (float*)d_ws;
    transpose_kernel<<<B_ * H_ * (W_ / 64), 256, 0, stream>>>(features, featT);
    eval_kernel<true><<<npix / 256, 256, 0, stream>>>(featT, offset_x, offset_y,
                                                      left_x, left_y, out);
  } else {
    eval_kernel<false><<<npix / 256, 256, 0, stream>>>(features, offset_x, offset_y,
                                                       left_x, left_y, out);
  }
}

// Round 2
// 685.162 us; speedup vs baseline: 1.2328x; 1.2328x over previous
//
#include <hip/hip_runtime.h>
#include <math.h>

#define B_ 2
#define C_ 36
#define H_ 512
#define W_ 512
#define K_ 9
#define HW_ (H_ * W_)

// ---------------------------------------------------------------------------
// Transpose features [B,C,H,W] -> [B,H,W,C] so one sample position's 36
// channels (and the adjacent column's) are one contiguous 288-byte run.
// ---------------------------------------------------------------------------
__global__ __launch_bounds__(256) void transpose_kernel(const float* __restrict__ in,
                                                        float* __restrict__ out) {
  __shared__ float tile[64][37];  // +1 pad: conflict-free
  int blk = blockIdx.x;           // ((b*H + h)*8 + wt)
  int wt = blk & 7;
  int h = (blk >> 3) & (H_ - 1);
  int b = blk >> 12;
  int w0 = wt << 6;
  int tid = threadIdx.x;
  const float* src = in + ((size_t)b * C_) * HW_ + (size_t)h * W_ + w0;
#pragma unroll
  for (int it = 0; it < 9; ++it) {  // 36 ch * 64 w = 2304 elems / 256 thr
    int idx = it * 256 + tid;
    int c = idx >> 6;
    int wl = idx & 63;
    tile[wl][c] = src[(size_t)c * HW_ + wl];
  }
  __syncthreads();
  float* dst = out + (((size_t)b * H_ + h) * W_ + w0) * C_;
#pragma unroll
  for (int it = 0; it < 9; ++it) {
    int idx = it * 256 + tid;
    int wl = idx / 36;
    int c = idx - wl * 36;
    dst[idx] = tile[wl][c];
  }
}

// ---------------------------------------------------------------------------
// Main kernel, 2D-tiled: block = 16x16 pixel tile. blockIdx%8 selects one of
// 8 fixed 256x256-px regions (2 batches x 4 quadrants) so each XCD's L2 sees
// a compact, serpentine-ordered sample footprint.
// feat is [B,H,W,C] (transposed scratch).
// ---------------------------------------------------------------------------
__global__ __launch_bounds__(256) void eval_kernel_t(const float* __restrict__ feat,
                                                     const float* __restrict__ offx,
                                                     const float* __restrict__ offy,
                                                     float* __restrict__ out) {
  int blk = blockIdx.x;      // 0..2047
  int region = blk & 7;      // -> XCD (dispatch round-robin residue)
  int slot = blk >> 3;       // 0..255 within region
  int b = region >> 2;       // batch
  int q = region & 3;        // quadrant
  int qy = (q >> 1) << 8;
  int qx = (q & 1) << 8;
  int tr = slot >> 4;        // tile row 0..15
  int tc = slot & 15;        // tile col
  if (tr & 1) tc = 15 - tc;  // serpentine for window overlap
  int h = qy + tr * 16 + (threadIdx.x >> 4);
  int w = qx + tc * 16 + (threadIdx.x & 15);
  int ph = h * W_ + w;
  int p = b * HW_ + ph;

  // center-pixel features: 36 ch contiguous, 16B-aligned (144B per pixel)
  float F[C_];
  {
    const float4* fb = reinterpret_cast<const float4*>(feat + (size_t)p * C_);
#pragma unroll
    for (int qq = 0; qq < 9; ++qq) {
      float4 v = fb[qq];
      F[4 * qq + 0] = v.x; F[4 * qq + 1] = v.y; F[4 * qq + 2] = v.z; F[4 * qq + 3] = v.w;
    }
  }

  float lx = (float)w;  // left_x == broadcast arange(W), exact in fp32
  float ly = (float)h;

  const float* oxb = offx + (size_t)b * K_ * HW_ + ph;
  const float* oyb = offy + (size_t)b * K_ * HW_ + ph;

  // online softmax state (temp-1000 logits)
  float M = -INFINITY, den = 0.f, ax = 0.f, ay = 0.f;

#pragma unroll 1
  for (int k = 0; k < K_; ++k) {
    float ox = oxb[k * HW_];
    float oy = oyb[k * HW_];
    // replicate reference fp32 chain: clip -> normalize -> denormalize
    float rx = fminf(fmaxf(lx + ox, 0.0f), 511.0f);
    float ry = fminf(fmaxf(ly + oy, 0.0f), 511.0f);
    float gx = (rx - 255.5f) / 255.5f;
    float gy = (ry - 255.5f) / 255.5f;
    float px = (gx + 1.0f) * 0.5f * 511.0f;
    float py = (gy + 1.0f) * 0.5f * 511.0f;
    // clamp corner to <=510, fold border into weight (bit-equivalent)
    int x0 = (int)floorf(px); x0 = (x0 > W_ - 2) ? (W_ - 2) : x0;
    int y0 = (int)floorf(py); y0 = (y0 > H_ - 2) ? (H_ - 2) : y0;
    float wx = px - (float)x0;
    float wy = py - (float)y0;
    float w00 = (1.0f - wx) * (1.0f - wy);
    float w01 = wx * (1.0f - wy);
    float w10 = (1.0f - wx) * wy;
    float w11 = wx * wy;

    float D[9] = {0.f, 0.f, 0.f, 0.f, 0.f, 0.f, 0.f, 0.f, 0.f};

    const float* r0 = feat + (((size_t)(b * H_ + y0)) * W_ + x0) * C_;
    const float* r1 = r0 + (size_t)W_ * C_;
#pragma unroll
    for (int qq = 0; qq < 9; ++qq) {
      float4 a00 = *reinterpret_cast<const float4*>(r0 + 4 * qq);       // col x0
      float4 a01 = *reinterpret_cast<const float4*>(r0 + C_ + 4 * qq);  // col x0+1
      float4 a10 = *reinterpret_cast<const float4*>(r1 + 4 * qq);
      float4 a11 = *reinterpret_cast<const float4*>(r1 + C_ + 4 * qq);
      float t00[4] = {a00.x, a00.y, a00.z, a00.w};
      float t01[4] = {a01.x, a01.y, a01.z, a01.w};
      float t10[4] = {a10.x, a10.y, a10.z, a10.w};
      float t11[4] = {a11.x, a11.y, a11.z, a11.w};
#pragma unroll
      for (int j = 0; j < 4; ++j) {
        int c = 4 * qq + j;
        float a = t00[j] * w00 + t01[j] * w01 + t10[j] * w10 + t11[j] * w11;
        int i = c % 12;
        int ga = c / 12;
        D[ga]     += fabsf(F[i]      - a);
        D[3 + ga] += fabsf(F[12 + i] - a);
        D[6 + ga] += fabsf(F[24 + i] - a);
      }
    }

    float mn = D[0];
#pragma unroll
    for (int j = 1; j < 9; ++j) mn = fminf(mn, D[j]);
    float xk = -(mn / 12.0f) * 1000.0f;

    float nm = fmaxf(M, xk);
    float sc = expf(M - nm);
    float ek = expf(xk - nm);
    den = den * sc + ek;
    ax = ax * sc + ox * ek;
    ay = ay * sc + oy * ek;
    M = nm;
  }

  float resx = ax / den;
  float resy = ay / den;
  float o0 = fminf(fmaxf(resx + lx, 0.0f), 511.0f) - lx;
  float o1 = fminf(fmaxf(resy + ly, 0.0f), 511.0f) - ly;
  out[p] = o0;
  out[B_ * HW_ + p] = o1;
}

// Fallback (no scratch): original channel-major layout, linear blocks.
__global__ __launch_bounds__(256) void eval_kernel_n(const float* __restrict__ feat,
                                                     const float* __restrict__ offx,
                                                     const float* __restrict__ offy,
                                                     float* __restrict__ out) {
  int p = blockIdx.x * 256 + threadIdx.x;
  int ph = p & (HW_ - 1);
  int b = p >> 18;
  float F[C_];
  const float* fb = feat + (size_t)b * C_ * HW_ + ph;
#pragma unroll
  for (int c = 0; c < C_; ++c) F[c] = fb[(size_t)c * HW_];
  float lx = (float)(ph & (W_ - 1));
  float ly = (float)((ph >> 9) & (H_ - 1));
  const float* oxb = offx + (size_t)b * K_ * HW_ + ph;
  const float* oyb = offy + (size_t)b * K_ * HW_ + ph;
  float M = -INFINITY, den = 0.f, ax = 0.f, ay = 0.f;
#pragma unroll 1
  for (int k = 0; k < K_; ++k) {
    float ox = oxb[k * HW_];
    float oy = oyb[k * HW_];
    float rx = fminf(fmaxf(lx + ox, 0.0f), 511.0f);
    float ry = fminf(fmaxf(ly + oy, 0.0f), 511.0f);
    float gx = (rx - 255.5f) / 255.5f;
    float gy = (ry - 255.5f) / 255.5f;
    float px = (gx + 1.0f) * 0.5f * 511.0f;
    float py = (gy + 1.0f) * 0.5f * 511.0f;
    int x0 = (int)floorf(px); x0 = (x0 > W_ - 2) ? (W_ - 2) : x0;
    int y0 = (int)floorf(py); y0 = (y0 > H_ - 2) ? (H_ - 2) : y0;
    float wx = px - (float)x0;
    float wy = py - (float)y0;
    float w00 = (1.0f - wx) * (1.0f - wy);
    float w01 = wx * (1.0f - wy);
    float w10 = (1.0f - wx) * wy;
    float w11 = wx * wy;
    float D[9] = {0.f, 0.f, 0.f, 0.f, 0.f, 0.f, 0.f, 0.f, 0.f};
    const float* pl = feat + (size_t)b * C_ * HW_ + (size_t)y0 * W_ + x0;
#pragma unroll
    for (int c = 0; c < C_; ++c) {
      const float* q0 = pl + (size_t)c * HW_;
      float v00 = q0[0], v01 = q0[1];
      float v10 = q0[W_], v11 = q0[W_ + 1];
      float a = v00 * w00 + v01 * w01 + v10 * w10 + v11 * w11;
      int i = c % 12;
      int ga = c / 12;
      D[ga]     += fabsf(F[i]      - a);
      D[3 + ga] += fabsf(F[12 + i] - a);
      D[6 + ga] += fabsf(F[24 + i] - a);
    }
    float mn = D[0];
#pragma unroll
    for (int j = 1; j < 9; ++j) mn = fminf(mn, D[j]);
    float xk = -(mn / 12.0f) * 1000.0f;
    float nm = fmaxf(M, xk);
    float sc = expf(M - nm);
    float ek = expf(xk - nm);
    den = den * sc + ek;
    ax = ax * sc + ox * ek;
    ay = ay * sc + oy * ek;
    M = nm;
  }
  float resx = ax / den;
  float resy = ay / den;
  out[p] = fminf(fmaxf(resx + lx, 0.0f), 511.0f) - lx;
  out[B_ * HW_ + p] = fminf(fmaxf(resy + ly, 0.0f), 511.0f) - ly;
}

extern "C" void kernel_launch(void* const* d_in, const int* in_sizes, int n_in,
                              void* d_out, int out_size, void* d_ws, size_t ws_size,
                              hipStream_t stream) {
  const float* features = (const float*)d_in[0];
  const float* offset_x = (const float*)d_in[1];
  const float* offset_y = (const float*)d_in[2];
  float* out = (float*)d_out;

  const int npix = B_ * HW_;  // 524288
  const size_t need = (size_t)npix * C_ * sizeof(float);  // 75.5 MB

  if (ws_size >= need) {
    float* featT = (float*)d_ws;
    transpose_kernel<<<B_ * H_ * (W_ / 64), 256, 0, stream>>>(features, featT);
    eval_kernel_t<<<npix / 256, 256, 0, stream>>>(featT, offset_x, offset_y, out);
  } else {
    eval_kernel_n<<<npix / 256, 256, 0, stream>>>(features, offset_x, offset_y, out);
  }
}

// Round 3
// 349.095 us; speedup vs baseline: 2.4196x; 1.9627x over previous
//
#include <hip/hip_runtime.h>
#include <math.h>

#define B_ 2
#define C_ 36
#define H_ 512
#define W_ 512
#define K_ 9
#define HW_ (H_ * W_)
#define ROWF4 (W_ * C_ / 4)  // float4 pitch of one image row in featT = 4608

// ---------------------------------------------------------------------------
// Transpose features [B,C,H,W] -> [B,H,W,C].
// ---------------------------------------------------------------------------
__global__ __launch_bounds__(256) void transpose_kernel(const float* __restrict__ in,
                                                        float* __restrict__ out) {
  __shared__ float tile[64][37];
  int blk = blockIdx.x;  // ((b*H + h)*8 + wt)
  int wt = blk & 7;
  int h = (blk >> 3) & (H_ - 1);
  int b = blk >> 12;
  int w0 = wt << 6;
  int tid = threadIdx.x;
  const float* src = in + ((size_t)b * C_) * HW_ + (size_t)h * W_ + w0;
#pragma unroll
  for (int it = 0; it < 9; ++it) {
    int idx = it * 256 + tid;
    int c = idx >> 6;
    int wl = idx & 63;
    tile[wl][c] = src[(size_t)c * HW_ + wl];
  }
  __syncthreads();
  float* dst = out + (((size_t)b * H_ + h) * W_ + w0) * C_;
#pragma unroll
  for (int it = 0; it < 9; ++it) {
    int idx = it * 256 + tid;
    int wl = idx / 36;
    int c = idx - wl * 36;
    dst[idx] = tile[wl][c];
  }
}

// ---------------------------------------------------------------------------
// Wave-cooperative eval: block = 1 wave = 64 threads = 8x8 pixel tile.
// Per candidate k: each lane computes its own pixel's corner/weights (meta in
// LDS), then the wave re-roles as 7 groups x 9 lanes and processes the 64
// (pixel,k) tasks in 10 rounds with CONTIGUOUS per-group float4 gathers.
// Group-of-9 cross-lane reduction via __shfl; per-task logit to LDS; owner
// lane finishes with the softmax.
// ---------------------------------------------------------------------------
__global__ __launch_bounds__(64) void eval_kernel_cw(const float* __restrict__ feat,
                                                     const float* __restrict__ offx,
                                                     const float* __restrict__ offy,
                                                     float* __restrict__ out) {
  __shared__ __align__(16) float F_lds[64 * 36];  // center features, pitch 36
  __shared__ __align__(16) float4 w_lds[64];      // bilinear weights per task
  __shared__ int a_lds[64];                       // row0-run float4 base index
  __shared__ float xk_lds[64 * 9];                // logits [pixel][k]

  int tid = threadIdx.x;
  int blk = blockIdx.x;
  int region = blk & 7;  // XCD round-robin residue -> fixed 256x256 region
  int slot = blk >> 3;   // 0..1023 within region
  int b = region >> 2;
  int qd = region & 3;
  int qy = (qd >> 1) << 8;
  int qx = (qd & 1) << 8;
  int tr = slot >> 5;  // 0..31
  int tc = slot & 31;
  if (tr & 1) tc = 31 - tc;  // serpentine for window overlap on same XCD
  int h = qy + tr * 8 + (tid >> 3);
  int w = qx + tc * 8 + (tid & 7);
  int ph = h * W_ + w;
  int p = b * HW_ + ph;

  const float4* feat4 = reinterpret_cast<const float4*>(feat);

  // stage own pixel's 36 center features into LDS (pitch 36 floats, 16B-align)
  {
    const float4* myF = feat4 + (size_t)p * 9;
#pragma unroll
    for (int i = 0; i < 9; ++i) {
      float4 v = myF[i];
      *reinterpret_cast<float4*>(&F_lds[tid * 36 + 4 * i]) = v;
    }
  }

  int g = tid / 9;       // 0..7 (g==7: lane 63, idle group)
  int q = tid - 9 * g;   // 0..8 channel-quad within task
  int qm3 = q % 3;
  int fofs = 4 * qm3;    // F offset within a 12-channel group

  float lx = (float)w;
  float ly = (float)h;
  const float* oxb = offx + (size_t)b * K_ * HW_ + ph;
  const float* oyb = offy + (size_t)b * K_ * HW_ + ph;

  __syncthreads();  // F_lds visible

#pragma unroll 1
  for (int k = 0; k < K_; ++k) {
    // --- owner role: my pixel's candidate-k meta ---
    float ox = oxb[k * HW_];
    float oy = oyb[k * HW_];
    float rx = fminf(fmaxf(lx + ox, 0.0f), 511.0f);
    float ry = fminf(fmaxf(ly + oy, 0.0f), 511.0f);
    float gx = (rx - 255.5f) / 255.5f;
    float gy = (ry - 255.5f) / 255.5f;
    float px = (gx + 1.0f) * 0.5f * 511.0f;
    float py = (gy + 1.0f) * 0.5f * 511.0f;
    int x0 = (int)floorf(px); x0 = (x0 > 510) ? 510 : x0;
    int y0 = (int)floorf(py); y0 = (y0 > 510) ? 510 : y0;
    float wx = px - (float)x0;
    float wy = py - (float)y0;
    float4 wv = make_float4((1.0f - wx) * (1.0f - wy), wx * (1.0f - wy),
                            (1.0f - wx) * wy, wx * wy);
    w_lds[tid] = wv;
    a_lds[tid] = ((b * H_ + y0) * W_ + x0) * 9;  // float4 index of row0 run
    __syncthreads();

    // --- gather role: 10 rounds x 7 tasks ---
    for (int r = 0; r < 10; ++r) {
      int tt = 7 * r + g;
      int t = (tt > 63) ? 63 : tt;  // clamped lanes compute garbage, unused
      int tb = a_lds[t];
      float4 W4 = w_lds[t];
      const float4* r0 = feat4 + tb;
      float4 v00 = r0[q];                // row y0, col x0, channels 4q..4q+3
      float4 v01 = r0[9 + q];            // row y0, col x0+1
      float4 v10 = r0[ROWF4 + q];        // row y0+1, col x0
      float4 v11 = r0[ROWF4 + 9 + q];    // row y0+1, col x0+1
      float4 a4;
      a4.x = W4.x * v00.x + W4.y * v01.x + W4.z * v10.x + W4.w * v11.x;
      a4.y = W4.x * v00.y + W4.y * v01.y + W4.z * v10.y + W4.w * v11.y;
      a4.z = W4.x * v00.z + W4.y * v01.z + W4.z * v10.z + W4.w * v11.z;
      a4.w = W4.x * v00.w + W4.y * v01.w + W4.z * v10.w + W4.w * v11.w;
      const float* fl = &F_lds[t * 36 + fofs];
      float4 f0 = *reinterpret_cast<const float4*>(fl);
      float4 f1 = *reinterpret_cast<const float4*>(fl + 12);
      float4 f2 = *reinterpret_cast<const float4*>(fl + 24);
      float pf0 = fabsf(f0.x - a4.x) + fabsf(f0.y - a4.y) +
                  fabsf(f0.z - a4.z) + fabsf(f0.w - a4.w);
      float pf1 = fabsf(f1.x - a4.x) + fabsf(f1.y - a4.y) +
                  fabsf(f1.z - a4.z) + fabsf(f1.w - a4.w);
      float pf2 = fabsf(f2.x - a4.x) + fabsf(f2.y - a4.y) +
                  fabsf(f2.z - a4.z) + fabsf(f2.w - a4.w);
      // sum over the 3 lanes of each channel-group (valid at q in {0,3,6})
      float d0 = pf0 + __shfl(pf0, tid + 1) + __shfl(pf0, tid + 2);
      float d1 = pf1 + __shfl(pf1, tid + 1) + __shfl(pf1, tid + 2);
      float d2 = pf2 + __shfl(pf2, tid + 1) + __shfl(pf2, tid + 2);
      float mn3 = fminf(d0, fminf(d1, d2));  // min over gf for my ga
      // min across ga (valid at q==0)
      float mn = fminf(mn3, fminf(__shfl(mn3, tid + 3), __shfl(mn3, tid + 6)));
      if (q == 0 && g < 7 && tt < 64) {
        xk_lds[tt * 9 + k] = -(mn / 12.0f) * 1000.0f;
      }
    }
    __syncthreads();  // xk done; protect meta WAR for next k
  }

  // --- owner role: softmax over my pixel's 9 logits ---
  float M = -INFINITY;
#pragma unroll
  for (int k = 0; k < K_; ++k) M = fmaxf(M, xk_lds[tid * 9 + k]);
  float den = 0.f, ax = 0.f, ay = 0.f;
#pragma unroll
  for (int k = 0; k < K_; ++k) {
    float e = expf(xk_lds[tid * 9 + k] - M);
    den += e;
    ax += e * oxb[k * HW_];
    ay += e * oyb[k * HW_];
  }
  float resx = ax / den;
  float resy = ay / den;
  out[p] = fminf(fmaxf(resx + lx, 0.0f), 511.0f) - lx;
  out[B_ * HW_ + p] = fminf(fmaxf(resy + ly, 0.0f), 511.0f) - ly;
}

// Fallback (no scratch): original channel-major layout, thread-per-pixel.
__global__ __launch_bounds__(256) void eval_kernel_n(const float* __restrict__ feat,
                                                     const float* __restrict__ offx,
                                                     const float* __restrict__ offy,
                                                     float* __restrict__ out) {
  int p = blockIdx.x * 256 + threadIdx.x;
  int ph = p & (HW_ - 1);
  int b = p >> 18;
  float F[C_];
  const float* fb = feat + (size_t)b * C_ * HW_ + ph;
#pragma unroll
  for (int c = 0; c < C_; ++c) F[c] = fb[(size_t)c * HW_];
  float lx = (float)(ph & (W_ - 1));
  float ly = (float)((ph >> 9) & (H_ - 1));
  const float* oxb = offx + (size_t)b * K_ * HW_ + ph;
  const float* oyb = offy + (size_t)b * K_ * HW_ + ph;
  float M = -INFINITY, den = 0.f, ax = 0.f, ay = 0.f;
#pragma unroll 1
  for (int k = 0; k < K_; ++k) {
    float ox = oxb[k * HW_];
    float oy = oyb[k * HW_];
    float rx = fminf(fmaxf(lx + ox, 0.0f), 511.0f);
    float ry = fminf(fmaxf(ly + oy, 0.0f), 511.0f);
    float gx = (rx - 255.5f) / 255.5f;
    float gy = (ry - 255.5f) / 255.5f;
    float px = (gx + 1.0f) * 0.5f * 511.0f;
    float py = (gy + 1.0f) * 0.5f * 511.0f;
    int x0 = (int)floorf(px); x0 = (x0 > 510) ? 510 : x0;
    int y0 = (int)floorf(py); y0 = (y0 > 510) ? 510 : y0;
    float wx = px - (float)x0;
    float wy = py - (float)y0;
    float w00 = (1.0f - wx) * (1.0f - wy);
    float w01 = wx * (1.0f - wy);
    float w10 = (1.0f - wx) * wy;
    float w11 = wx * wy;
    float D[9] = {0.f, 0.f, 0.f, 0.f, 0.f, 0.f, 0.f, 0.f, 0.f};
    const float* pl = feat + (size_t)b * C_ * HW_ + (size_t)y0 * W_ + x0;
#pragma unroll
    for (int c = 0; c < C_; ++c) {
      const float* q0 = pl + (size_t)c * HW_;
      float v00 = q0[0], v01 = q0[1];
      float v10 = q0[W_], v11 = q0[W_ + 1];
      float a = v00 * w00 + v01 * w01 + v10 * w10 + v11 * w11;
      int i = c % 12;
      int ga = c / 12;
      D[ga]     += fabsf(F[i]      - a);
      D[3 + ga] += fabsf(F[12 + i] - a);
      D[6 + ga] += fabsf(F[24 + i] - a);
    }
    float mn = D[0];
#pragma unroll
    for (int j = 1; j < 9; ++j) mn = fminf(mn, D[j]);
    float xk = -(mn / 12.0f) * 1000.0f;
    float nm = fmaxf(M, xk);
    float sc = expf(M - nm);
    float ek = expf(xk - nm);
    den = den * sc + ek;
    ax = ax * sc + ox * ek;
    ay = ay * sc + oy * ek;
    M = nm;
  }
  float resx = ax / den;
  float resy = ay / den;
  out[p] = fminf(fmaxf(resx + lx, 0.0f), 511.0f) - lx;
  out[B_ * HW_ + p] = fminf(fmaxf(resy + ly, 0.0f), 511.0f) - ly;
}

extern "C" void kernel_launch(void* const* d_in, const int* in_sizes, int n_in,
                              void* d_out, int out_size, void* d_ws, size_t ws_size,
                              hipStream_t stream) {
  const float* features = (const float*)d_in[0];
  const float* offset_x = (const float*)d_in[1];
  const float* offset_y = (const float*)d_in[2];
  float* out = (float*)d_out;

  const int npix = B_ * HW_;  // 524288
  const size_t need = (size_t)npix * C_ * sizeof(float);  // 75.5 MB

  if (ws_size >= need) {
    float* featT = (float*)d_ws;
    transpose_kernel<<<B_ * H_ * (W_ / 64), 256, 0, stream>>>(features, featT);
    eval_kernel_cw<<<npix / 64, 64, 0, stream>>>(featT, offset_x, offset_y, out);
  } else {
    eval_kernel_n<<<npix / 256, 256, 0, stream>>>(features, offset_x, offset_y, out);
  }
}

// Round 4
// 342.039 us; speedup vs baseline: 2.4695x; 1.0206x over previous
//
#include <hip/hip_runtime.h>
#include <math.h>

#define B_ 2
#define C_ 36
#define H_ 512
#define W_ 512
#define K_ 9
#define HW_ (H_ * W_)
#define ROWF4 (W_ * C_ / 4)  // float4 pitch of one image row in featT = 4608

// ---------------------------------------------------------------------------
// Transpose features [B,C,H,W] -> [B,H,W,C].
// ---------------------------------------------------------------------------
__global__ __launch_bounds__(256) void transpose_kernel(const float* __restrict__ in,
                                                        float* __restrict__ out) {
  __shared__ float tile[64][37];
  int blk = blockIdx.x;  // ((b*H + h)*8 + wt)
  int wt = blk & 7;
  int h = (blk >> 3) & (H_ - 1);
  int b = blk >> 12;
  int w0 = wt << 6;
  int tid = threadIdx.x;
  const float* src = in + ((size_t)b * C_) * HW_ + (size_t)h * W_ + w0;
#pragma unroll
  for (int it = 0; it < 9; ++it) {
    int idx = it * 256 + tid;
    int c = idx >> 6;
    int wl = idx & 63;
    tile[wl][c] = src[(size_t)c * HW_ + wl];
  }
  __syncthreads();
  float* dst = out + (((size_t)b * H_ + h) * W_ + w0) * C_;
#pragma unroll
  for (int it = 0; it < 9; ++it) {
    int idx = it * 256 + tid;
    int wl = idx / 36;
    int c = idx - wl * 36;
    dst[idx] = tile[wl][c];
  }
}

// ---------------------------------------------------------------------------
// Wave-cooperative eval v2: block = 1 wave = 8x8 pixel tile.
// Gather lanes (7 groups x 9 quad-lanes) only bilinear-interpolate and write
// raw a4 quads to LDS scratch; the owner lane of each pixel reads its 9
// contiguous float4s back and does all |F-a| group-pair reductions with F in
// REGISTERS. No shuffles, no F in LDS, online softmax in owner registers.
// ---------------------------------------------------------------------------
__global__ __launch_bounds__(64, 4) void eval_kernel_cw(const float* __restrict__ feat,
                                                        const float* __restrict__ offx,
                                                        const float* __restrict__ offy,
                                                        float* __restrict__ out) {
  __shared__ __align__(16) float scratch[64 * 36];  // [task][36ch] interpolated
  __shared__ __align__(16) float4 w_lds[64];        // bilinear weights per task
  __shared__ int a_lds[64];                         // row0-run float4 base index

  int tid = threadIdx.x;
  int blk = blockIdx.x;
  int region = blk & 7;  // XCD round-robin residue -> fixed 256x256 region
  int slot = blk >> 3;   // 0..1023 within region
  int b = region >> 2;
  int qd = region & 3;
  int qy = (qd >> 1) << 8;
  int qx = (qd & 1) << 8;
  int tr = slot >> 5;  // 0..31
  int tc = slot & 31;
  if (tr & 1) tc = 31 - tc;  // serpentine for window overlap on same XCD
  int h = qy + tr * 8 + (tid >> 3);
  int w = qx + tc * 8 + (tid & 7);
  int ph = h * W_ + w;
  int p = b * HW_ + ph;

  const float4* feat4 = reinterpret_cast<const float4*>(feat);

  // own pixel's 36 center features -> registers
  float F[C_];
  {
    const float4* myF = feat4 + (size_t)p * 9;
#pragma unroll
    for (int i = 0; i < 9; ++i) {
      float4 v = myF[i];
      F[4 * i + 0] = v.x; F[4 * i + 1] = v.y; F[4 * i + 2] = v.z; F[4 * i + 3] = v.w;
    }
  }

  int g = tid / 9;      // gather group 0..7 (g==7 -> lane 63, writes suppressed)
  int q = tid - 9 * g;  // channel-quad within task

  float lx = (float)w;
  float ly = (float)h;
  const float* oxb = offx + (size_t)b * K_ * HW_ + ph;
  const float* oyb = offy + (size_t)b * K_ * HW_ + ph;

  float M = -INFINITY, den = 0.f, axs = 0.f, ays = 0.f;

#pragma unroll 1
  for (int k = 0; k < K_; ++k) {
    // --- owner role: candidate-k meta ---
    float ox = oxb[k * HW_];
    float oy = oyb[k * HW_];
    float rx = fminf(fmaxf(lx + ox, 0.0f), 511.0f);
    float ry = fminf(fmaxf(ly + oy, 0.0f), 511.0f);
    float gx = (rx - 255.5f) / 255.5f;
    float gy = (ry - 255.5f) / 255.5f;
    float px = (gx + 1.0f) * 0.5f * 511.0f;
    float py = (gy + 1.0f) * 0.5f * 511.0f;
    int x0 = (int)floorf(px); x0 = (x0 > 510) ? 510 : x0;
    int y0 = (int)floorf(py); y0 = (y0 > 510) ? 510 : y0;
    float wx = px - (float)x0;
    float wy = py - (float)y0;
    w_lds[tid] = make_float4((1.0f - wx) * (1.0f - wy), wx * (1.0f - wy),
                             (1.0f - wx) * wy, wx * wy);
    a_lds[tid] = ((b * H_ + y0) * W_ + x0) * 9;  // float4 index of row0 run
    __syncthreads();

    // --- gather role: 10 rounds x 7 tasks, contiguous float4 loads ---
    int tt = g;
#pragma unroll 1
    for (int r = 0; r < 10; ++r) {
      int t = (tt > 63) ? 63 : tt;
      int tb = a_lds[t];
      float4 W4 = w_lds[t];
      const float4* r0 = feat4 + tb;
      float4 v00 = r0[q];
      float4 v01 = r0[9 + q];
      float4 v10 = r0[ROWF4 + q];
      float4 v11 = r0[ROWF4 + 9 + q];
      float4 a4;
      a4.x = W4.x * v00.x + W4.y * v01.x + W4.z * v10.x + W4.w * v11.x;
      a4.y = W4.x * v00.y + W4.y * v01.y + W4.z * v10.y + W4.w * v11.y;
      a4.z = W4.x * v00.z + W4.y * v01.z + W4.z * v10.z + W4.w * v11.z;
      a4.w = W4.x * v00.w + W4.y * v01.w + W4.z * v10.w + W4.w * v11.w;
      if (tt < 64 && tid < 63) {
        *reinterpret_cast<float4*>(&scratch[t * 36 + 4 * q]) = a4;
      }
      tt += 7;
    }
    __syncthreads();

    // --- owner role: read my 36 interpolated channels, reduce, softmax ---
    float D[9] = {0.f, 0.f, 0.f, 0.f, 0.f, 0.f, 0.f, 0.f, 0.f};
    const float4* sc = reinterpret_cast<const float4*>(&scratch[tid * 36]);
#pragma unroll
    for (int q2 = 0; q2 < 9; ++q2) {
      float4 a4 = sc[q2];
      float av[4] = {a4.x, a4.y, a4.z, a4.w};
      int ga = q2 / 3;
      int f0 = 4 * (q2 % 3);
#pragma unroll
      for (int j = 0; j < 4; ++j) {
        D[ga]     += fabsf(F[f0 + j]      - av[j]);
        D[3 + ga] += fabsf(F[12 + f0 + j] - av[j]);
        D[6 + ga] += fabsf(F[24 + f0 + j] - av[j]);
      }
    }
    float mn = D[0];
#pragma unroll
    for (int j = 1; j < 9; ++j) mn = fminf(mn, D[j]);
    float xk = -(mn / 12.0f) * 1000.0f;

    float nm = fmaxf(M, xk);
    float scl = expf(M - nm);
    float ek = expf(xk - nm);
    den = den * scl + ek;
    axs = axs * scl + ox * ek;
    ays = ays * scl + oy * ek;
    M = nm;
  }

  float resx = axs / den;
  float resy = ays / den;
  out[p] = fminf(fmaxf(resx + lx, 0.0f), 511.0f) - lx;
  out[B_ * HW_ + p] = fminf(fmaxf(resy + ly, 0.0f), 511.0f) - ly;
}

// Fallback (no scratch): original channel-major layout, thread-per-pixel.
__global__ __launch_bounds__(256) void eval_kernel_n(const float* __restrict__ feat,
                                                     const float* __restrict__ offx,
                                                     const float* __restrict__ offy,
                                                     float* __restrict__ out) {
  int p = blockIdx.x * 256 + threadIdx.x;
  int ph = p & (HW_ - 1);
  int b = p >> 18;
  float F[C_];
  const float* fb = feat + (size_t)b * C_ * HW_ + ph;
#pragma unroll
  for (int c = 0; c < C_; ++c) F[c] = fb[(size_t)c * HW_];
  float lx = (float)(ph & (W_ - 1));
  float ly = (float)((ph >> 9) & (H_ - 1));
  const float* oxb = offx + (size_t)b * K_ * HW_ + ph;
  const float* oyb = offy + (size_t)b * K_ * HW_ + ph;
  float M = -INFINITY, den = 0.f, ax = 0.f, ay = 0.f;
#pragma unroll 1
  for (int k = 0; k < K_; ++k) {
    float ox = oxb[k * HW_];
    float oy = oyb[k * HW_];
    float rx = fminf(fmaxf(lx + ox, 0.0f), 511.0f);
    float ry = fminf(fmaxf(ly + oy, 0.0f), 511.0f);
    float gx = (rx - 255.5f) / 255.5f;
    float gy = (ry - 255.5f) / 255.5f;
    float px = (gx + 1.0f) * 0.5f * 511.0f;
    float py = (gy + 1.0f) * 0.5f * 511.0f;
    int x0 = (int)floorf(px); x0 = (x0 > 510) ? 510 : x0;
    int y0 = (int)floorf(py); y0 = (y0 > 510) ? 510 : y0;
    float wx = px - (float)x0;
    float wy = py - (float)y0;
    float w00 = (1.0f - wx) * (1.0f - wy);
    float w01 = wx * (1.0f - wy);
    float w10 = (1.0f - wx) * wy;
    float w11 = wx * wy;
    float D[9] = {0.f, 0.f, 0.f, 0.f, 0.f, 0.f, 0.f, 0.f, 0.f};
    const float* pl = feat + (size_t)b * C_ * HW_ + (size_t)y0 * W_ + x0;
#pragma unroll
    for (int c = 0; c < C_; ++c) {
      const float* q0 = pl + (size_t)c * HW_;
      float v00 = q0[0], v01 = q0[1];
      float v10 = q0[W_], v11 = q0[W_ + 1];
      float a = v00 * w00 + v01 * w01 + v10 * w10 + v11 * w11;
      int i = c % 12;
      int ga = c / 12;
      D[ga]     += fabsf(F[i]      - a);
      D[3 + ga] += fabsf(F[12 + i] - a);
      D[6 + ga] += fabsf(F[24 + i] - a);
    }
    float mn = D[0];
#pragma unroll
    for (int j = 1; j < 9; ++j) mn = fminf(mn, D[j]);
    float xk = -(mn / 12.0f) * 1000.0f;
    float nm = fmaxf(M, xk);
    float sc = expf(M - nm);
    float ek = expf(xk - nm);
    den = den * sc + ek;
    ax = ax * sc + ox * ek;
    ay = ay * sc + oy * ek;
    M = nm;
  }
  float resx = ax / den;
  float resy = ay / den;
  out[p] = fminf(fmaxf(resx + lx, 0.0f), 511.0f) - lx;
  out[B_ * HW_ + p] = fminf(fmaxf(resy + ly, 0.0f), 511.0f) - ly;
}

extern "C" void kernel_launch(void* const* d_in, const int* in_sizes, int n_in,
                              void* d_out, int out_size, void* d_ws, size_t ws_size,
                              hipStream_t stream) {
  const float* features = (const float*)d_in[0];
  const float* offset_x = (const float*)d_in[1];
  const float* offset_y = (const float*)d_in[2];
  float* out = (float*)d_out;

  const int npix = B_ * HW_;  // 524288
  const size_t need = (size_t)npix * C_ * sizeof(float);  // 75.5 MB

  if (ws_size >= need) {
    float* featT = (float*)d_ws;
    transpose_kernel<<<B_ * H_ * (W_ / 64), 256, 0, stream>>>(features, featT);
    eval_kernel_cw<<<npix / 64, 64, 0, stream>>>(featT, offset_x, offset_y, out);
  } else {
    eval_kernel_n<<<npix / 256, 256, 0, stream>>>(features, offset_x, offset_y, out);
  }
}

// Round 5
// 321.435 us; speedup vs baseline: 2.6278x; 1.0641x over previous
//
#include <hip/hip_runtime.h>
#include <math.h>

#define B_ 2
#define C_ 36
#define H_ 512
#define W_ 512
#define K_ 9
#define HW_ (H_ * W_)
#define ROWF4 (W_ * C_ / 4)  // float4 pitch of one image row in featT = 4608

// ---------------------------------------------------------------------------
// Transpose features [B,C,H,W] -> [B,H,W,C].
// ---------------------------------------------------------------------------
__global__ __launch_bounds__(256) void transpose_kernel(const float* __restrict__ in,
                                                        float* __restrict__ out) {
  __shared__ float tile[64][37];
  int blk = blockIdx.x;  // ((b*H + h)*8 + wt)
  int wt = blk & 7;
  int h = (blk >> 3) & (H_ - 1);
  int b = blk >> 12;
  int w0 = wt << 6;
  int tid = threadIdx.x;
  const float* src = in + ((size_t)b * C_) * HW_ + (size_t)h * W_ + w0;
#pragma unroll
  for (int it = 0; it < 9; ++it) {
    int idx = it * 256 + tid;
    int c = idx >> 6;
    int wl = idx & 63;
    tile[wl][c] = src[(size_t)c * HW_ + wl];
  }
  __syncthreads();
  float* dst = out + (((size_t)b * H_ + h) * W_ + w0) * C_;
#pragma unroll
  for (int it = 0; it < 9; ++it) {
    int idx = it * 256 + tid;
    int wl = idx / 36;
    int c = idx - wl * 36;
    dst[idx] = tile[wl][c];
  }
}

// ---------------------------------------------------------------------------
// Wave-cooperative eval v3: block = 1 wave = 8x8 pixel tile.
// Same task split as v2 (7 groups x 9 quad-lanes gather; owner lane reduces),
// but the 10 gather rounds are SOFTWARE-PIPELINED with an explicit depth-5
// register window so ~20 independent global loads are in flight per lane.
// Grid caps us at 2 waves/SIMD, so VGPRs (up to 256) are free — spend them
// on MLP to hide the ~700-cycle L2/L3 miss latency.
// ---------------------------------------------------------------------------
__global__ __launch_bounds__(64, 2) void eval_kernel_cw(const float* __restrict__ feat,
                                                        const float* __restrict__ offx,
                                                        const float* __restrict__ offy,
                                                        float* __restrict__ out) {
  __shared__ __align__(16) float scratch[64 * 36];  // [task][36ch] interpolated
  __shared__ __align__(16) float4 w_lds[64];        // bilinear weights per task
  __shared__ int a_lds[64];                         // row0-run float4 base index

  int tid = threadIdx.x;
  int blk = blockIdx.x;
  int region = blk & 7;  // XCD round-robin residue -> fixed 256x256 region
  int slot = blk >> 3;   // 0..1023 within region
  int b = region >> 2;
  int qd = region & 3;
  int qy = (qd >> 1) << 8;
  int qx = (qd & 1) << 8;
  int tr = slot >> 5;  // 0..31
  int tc = slot & 31;
  if (tr & 1) tc = 31 - tc;  // serpentine for window overlap on same XCD
  int h = qy + tr * 8 + (tid >> 3);
  int w = qx + tc * 8 + (tid & 7);
  int ph = h * W_ + w;
  int p = b * HW_ + ph;

  const float4* feat4 = reinterpret_cast<const float4*>(feat);

  // all 9 candidates' offsets up front (independent loads, hide latency)
  const float* oxb = offx + (size_t)b * K_ * HW_ + ph;
  const float* oyb = offy + (size_t)b * K_ * HW_ + ph;
  float oxv[K_], oyv[K_];
#pragma unroll
  for (int k = 0; k < K_; ++k) {
    oxv[k] = oxb[k * HW_];
    oyv[k] = oyb[k * HW_];
  }

  // own pixel's 36 center features -> registers
  float F[C_];
  {
    const float4* myF = feat4 + (size_t)p * 9;
#pragma unroll
    for (int i = 0; i < 9; ++i) {
      float4 v = myF[i];
      F[4 * i + 0] = v.x; F[4 * i + 1] = v.y; F[4 * i + 2] = v.z; F[4 * i + 3] = v.w;
    }
  }

  int g = tid / 9;      // gather group 0..7 (g==7 -> lane 63, writes suppressed)
  int q = tid - 9 * g;  // channel-quad within task

  float lx = (float)w;
  float ly = (float)h;

  float M = -INFINITY, den = 0.f, axs = 0.f, ays = 0.f;

#pragma unroll 1
  for (int k = 0; k < K_; ++k) {
    // --- owner role: candidate-k meta ---
    float ox = oxv[k];
    float oy = oyv[k];
    float rx = fminf(fmaxf(lx + ox, 0.0f), 511.0f);
    float ry = fminf(fmaxf(ly + oy, 0.0f), 511.0f);
    float gx = (rx - 255.5f) / 255.5f;
    float gy = (ry - 255.5f) / 255.5f;
    float px = (gx + 1.0f) * 0.5f * 511.0f;
    float py = (gy + 1.0f) * 0.5f * 511.0f;
    int x0 = (int)floorf(px); x0 = (x0 > 510) ? 510 : x0;
    int y0 = (int)floorf(py); y0 = (y0 > 510) ? 510 : y0;
    float wx = px - (float)x0;
    float wy = py - (float)y0;
    w_lds[tid] = make_float4((1.0f - wx) * (1.0f - wy), wx * (1.0f - wy),
                             (1.0f - wx) * wy, wx * wy);
    a_lds[tid] = ((b * H_ + y0) * W_ + x0) * 9;  // float4 index of row0 run
    __syncthreads();

    // --- gather role: 10 rounds, depth-5 pipelined window ---
    float4 L[5][4];
#pragma unroll
    for (int r = 0; r < 5; ++r) {
      int tt = 7 * r + g;
      int t = (tt > 63) ? 63 : tt;
      const float4* r0 = feat4 + a_lds[t];
      L[r][0] = r0[q];
      L[r][1] = r0[9 + q];
      L[r][2] = r0[ROWF4 + q];
      L[r][3] = r0[ROWF4 + 9 + q];
    }
#pragma unroll
    for (int r = 0; r < 10; ++r) {
      int s = r % 5;
      int tt = 7 * r + g;
      int t = (tt > 63) ? 63 : tt;
      float4 W4 = w_lds[t];
      float4 v00 = L[s][0], v01 = L[s][1], v10 = L[s][2], v11 = L[s][3];
      float4 a4;
      a4.x = W4.x * v00.x + W4.y * v01.x + W4.z * v10.x + W4.w * v11.x;
      a4.y = W4.x * v00.y + W4.y * v01.y + W4.z * v10.y + W4.w * v11.y;
      a4.z = W4.x * v00.z + W4.y * v01.z + W4.z * v10.z + W4.w * v11.z;
      a4.w = W4.x * v00.w + W4.y * v01.w + W4.z * v10.w + W4.w * v11.w;
      if (tt < 64 && tid < 63) {
        *reinterpret_cast<float4*>(&scratch[t * 36 + 4 * q]) = a4;
      }
      if (r + 5 < 10) {
        int tt2 = 7 * (r + 5) + g;
        int t2 = (tt2 > 63) ? 63 : tt2;
        const float4* r0 = feat4 + a_lds[t2];
        L[s][0] = r0[q];
        L[s][1] = r0[9 + q];
        L[s][2] = r0[ROWF4 + q];
        L[s][3] = r0[ROWF4 + 9 + q];
      }
    }
    __syncthreads();

    // --- owner role: read my 36 interpolated channels, reduce, softmax ---
    float D[9] = {0.f, 0.f, 0.f, 0.f, 0.f, 0.f, 0.f, 0.f, 0.f};
    const float4* sc = reinterpret_cast<const float4*>(&scratch[tid * 36]);
#pragma unroll
    for (int q2 = 0; q2 < 9; ++q2) {
      float4 a4 = sc[q2];
      float av[4] = {a4.x, a4.y, a4.z, a4.w};
      int ga = q2 / 3;
      int f0 = 4 * (q2 % 3);
#pragma unroll
      for (int j = 0; j < 4; ++j) {
        D[ga]     += fabsf(F[f0 + j]      - av[j]);
        D[3 + ga] += fabsf(F[12 + f0 + j] - av[j]);
        D[6 + ga] += fabsf(F[24 + f0 + j] - av[j]);
      }
    }
    float mn = D[0];
#pragma unroll
    for (int j = 1; j < 9; ++j) mn = fminf(mn, D[j]);
    float xk = -(mn / 12.0f) * 1000.0f;

    float nm = fmaxf(M, xk);
    float scl = expf(M - nm);
    float ek = expf(xk - nm);
    den = den * scl + ek;
    axs = axs * scl + ox * ek;
    ays = ays * scl + oy * ek;
    M = nm;
  }

  float resx = axs / den;
  float resy = ays / den;
  out[p] = fminf(fmaxf(resx + lx, 0.0f), 511.0f) - lx;
  out[B_ * HW_ + p] = fminf(fmaxf(resy + ly, 0.0f), 511.0f) - ly;
}

// Fallback (no scratch): original channel-major layout, thread-per-pixel.
__global__ __launch_bounds__(256) void eval_kernel_n(const float* __restrict__ feat,
                                                     const float* __restrict__ offx,
                                                     const float* __restrict__ offy,
                                                     float* __restrict__ out) {
  int p = blockIdx.x * 256 + threadIdx.x;
  int ph = p & (HW_ - 1);
  int b = p >> 18;
  float F[C_];
  const float* fb = feat + (size_t)b * C_ * HW_ + ph;
#pragma unroll
  for (int c = 0; c < C_; ++c) F[c] = fb[(size_t)c * HW_];
  float lx = (float)(ph & (W_ - 1));
  float ly = (float)((ph >> 9) & (H_ - 1));
  const float* oxb = offx + (size_t)b * K_ * HW_ + ph;
  const float* oyb = offy + (size_t)b * K_ * HW_ + ph;
  float M = -INFINITY, den = 0.f, ax = 0.f, ay = 0.f;
#pragma unroll 1
  for (int k = 0; k < K_; ++k) {
    float ox = oxb[k * HW_];
    float oy = oyb[k * HW_];
    float rx = fminf(fmaxf(lx + ox, 0.0f), 511.0f);
    float ry = fminf(fmaxf(ly + oy, 0.0f), 511.0f);
    float gx = (rx - 255.5f) / 255.5f;
    float gy = (ry - 255.5f) / 255.5f;
    float px = (gx + 1.0f) * 0.5f * 511.0f;
    float py = (gy + 1.0f) * 0.5f * 511.0f;
    int x0 = (int)floorf(px); x0 = (x0 > 510) ? 510 : x0;
    int y0 = (int)floorf(py); y0 = (y0 > 510) ? 510 : y0;
    float wx = px - (float)x0;
    float wy = py - (float)y0;
    float w00 = (1.0f - wx) * (1.0f - wy);
    float w01 = wx * (1.0f - wy);
    float w10 = (1.0f - wx) * wy;
    float w11 = wx * wy;
    float D[9] = {0.f, 0.f, 0.f, 0.f, 0.f, 0.f, 0.f, 0.f, 0.f};
    const float* pl = feat + (size_t)b * C_ * HW_ + (size_t)y0 * W_ + x0;
#pragma unroll
    for (int c = 0; c < C_; ++c) {
      const float* q0 = pl + (size_t)c * HW_;
      float v00 = q0[0], v01 = q0[1];
      float v10 = q0[W_], v11 = q0[W_ + 1];
      float a = v00 * w00 + v01 * w01 + v10 * w10 + v11 * w11;
      int i = c % 12;
      int ga = c / 12;
      D[ga]     += fabsf(F[i]      - a);
      D[3 + ga] += fabsf(F[12 + i] - a);
      D[6 + ga] += fabsf(F[24 + i] - a);
    }
    float mn = D[0];
#pragma unroll
    for (int j = 1; j < 9; ++j) mn = fminf(mn, D[j]);
    float xk = -(mn / 12.0f) * 1000.0f;
    float nm = fmaxf(M, xk);
    float sc = expf(M - nm);
    float ek = expf(xk - nm);
    den = den * sc + ek;
    ax = ax * sc + ox * ek;
    ay = ay * sc + oy * ek;
    M = nm;
  }
  float resx = ax / den;
  float resy = ay / den;
  out[p] = fminf(fmaxf(resx + lx, 0.0f), 511.0f) - lx;
  out[B_ * HW_ + p] = fminf(fmaxf(resy + ly, 0.0f), 511.0f) - ly;
}

extern "C" void kernel_launch(void* const* d_in, const int* in_sizes, int n_in,
                              void* d_out, int out_size, void* d_ws, size_t ws_size,
                              hipStream_t stream) {
  const float* features = (const float*)d_in[0];
  const float* offset_x = (const float*)d_in[1];
  const float* offset_y = (const float*)d_in[2];
  float* out = (float*)d_out;

  const int npix = B_ * HW_;  // 524288
  const size_t need = (size_t)npix * C_ * sizeof(float);  // 75.5 MB

  if (ws_size >= need) {
    float* featT = (float*)d_ws;
    transpose_kernel<<<B_ * H_ * (W_ / 64), 256, 0, stream>>>(features, featT);
    eval_kernel_cw<<<npix / 64, 64, 0, stream>>>(featT, offset_x, offset_y, out);
  } else {
    eval_kernel_n<<<npix / 256, 256, 0, stream>>>(features, offset_x, offset_y, out);
  }
}

// Round 6
// 313.537 us; speedup vs baseline: 2.6940x; 1.0252x over previous
//
#include <hip/hip_runtime.h>
#include <math.h>

#define B_ 2
#define C_ 36
#define H_ 512
#define W_ 512
#define K_ 9
#define HW_ (H_ * W_)
#define ROWF4 (W_ * C_ / 4)  // float4 pitch of one image row in featT = 4608

// ---------------------------------------------------------------------------
// Transpose features [B,C,H,W] -> [B,H,W,C].
// ---------------------------------------------------------------------------
__global__ __launch_bounds__(256) void transpose_kernel(const float* __restrict__ in,
                                                        float* __restrict__ out) {
  __shared__ float tile[64][37];
  int blk = blockIdx.x;  // ((b*H + h)*8 + wt)
  int wt = blk & 7;
  int h = (blk >> 3) & (H_ - 1);
  int b = blk >> 12;
  int w0 = wt << 6;
  int tid = threadIdx.x;
  const float* src = in + ((size_t)b * C_) * HW_ + (size_t)h * W_ + w0;
#pragma unroll
  for (int it = 0; it < 9; ++it) {
    int idx = it * 256 + tid;
    int c = idx >> 6;
    int wl = idx & 63;
    tile[wl][c] = src[(size_t)c * HW_ + wl];
  }
  __syncthreads();
  float* dst = out + (((size_t)b * H_ + h) * W_ + w0) * C_;
#pragma unroll
  for (int it = 0; it < 9; ++it) {
    int idx = it * 256 + tid;
    int wl = idx / 36;
    int c = idx - wl * 36;
    dst[idx] = tile[wl][c];
  }
}

// ---------------------------------------------------------------------------
// Wave-cooperative eval v4: block = 1 wave = 8x8 pixel tile.
// Per candidate k, TWO gather phases (tasks 0-31, 32-63) with a flat 20-load
// register window each; phase-B loads are issued BEFORE the phase-A owner
// reduce so they overlap it. Single-wave blocks => DS ops are in-order per
// wave, so cross-lane LDS RAW is safe on program order alone; only one
// __syncthreads per k (after meta) remains, avoiding vmcnt(0) drains that
// would kill the prefetch. LDS ~5.9 KB doubles resident blocks.
// ---------------------------------------------------------------------------
__global__ __launch_bounds__(64, 2) void eval_kernel_cw(const float* __restrict__ feat,
                                                        const float* __restrict__ offx,
                                                        const float* __restrict__ offy,
                                                        float* __restrict__ out) {
  __shared__ __align__(16) float scratch[32 * 36];  // [task&31][36ch]
  __shared__ __align__(16) float4 w_lds[64];        // bilinear weights per task
  __shared__ int a_lds[64];                         // row0-run float4 base index

  int tid = threadIdx.x;
  int blk = blockIdx.x;
  int region = blk & 7;  // XCD round-robin residue -> fixed 256x256 region
  int slot = blk >> 3;   // 0..1023 within region
  int b = region >> 2;
  int qd = region & 3;
  int qy = (qd >> 1) << 8;
  int qx = (qd & 1) << 8;
  int tr = slot >> 5;  // 0..31
  int tc = slot & 31;
  if (tr & 1) tc = 31 - tc;  // serpentine for window overlap on same XCD
  int h = qy + tr * 8 + (tid >> 3);
  int w = qx + tc * 8 + (tid & 7);
  int ph = h * W_ + w;
  int p = b * HW_ + ph;

  const float4* feat4 = reinterpret_cast<const float4*>(feat);

  // all 9 candidates' offsets up front (independent loads)
  const float* oxb = offx + (size_t)b * K_ * HW_ + ph;
  const float* oyb = offy + (size_t)b * K_ * HW_ + ph;
  float oxv[K_], oyv[K_];
#pragma unroll
  for (int k = 0; k < K_; ++k) {
    oxv[k] = oxb[k * HW_];
    oyv[k] = oyb[k * HW_];
  }

  // own pixel's 36 center features -> registers
  float F[C_];
  {
    const float4* myF = feat4 + (size_t)p * 9;
#pragma unroll
    for (int i = 0; i < 9; ++i) {
      float4 v = myF[i];
      F[4 * i + 0] = v.x; F[4 * i + 1] = v.y; F[4 * i + 2] = v.z; F[4 * i + 3] = v.w;
    }
  }

  int g = tid / 9;      // gather group 0..7 (g==7 -> lane 63, stores suppressed)
  int q = tid - 9 * g;  // channel-quad within task

  float lx = (float)w;
  float ly = (float)h;

  float M = -INFINITY, den = 0.f, axs = 0.f, ays = 0.f;

#pragma unroll 1
  for (int k = 0; k < K_; ++k) {
    // --- meta for my task ---
    float ox = oxv[k];
    float oy = oyv[k];
    float rx = fminf(fmaxf(lx + ox, 0.0f), 511.0f);
    float ry = fminf(fmaxf(ly + oy, 0.0f), 511.0f);
    float gx = (rx - 255.5f) / 255.5f;
    float gy = (ry - 255.5f) / 255.5f;
    float px = (gx + 1.0f) * 0.5f * 511.0f;
    float py = (gy + 1.0f) * 0.5f * 511.0f;
    int x0 = (int)floorf(px); x0 = (x0 > 510) ? 510 : x0;
    int y0 = (int)floorf(py); y0 = (y0 > 510) ? 510 : y0;
    float wx = px - (float)x0;
    float wy = py - (float)y0;
    w_lds[tid] = make_float4((1.0f - wx) * (1.0f - wy), wx * (1.0f - wy),
                             (1.0f - wx) * wy, wx * wy);
    a_lds[tid] = ((b * H_ + y0) * W_ + x0) * 9;  // float4 index of row0 run
    __syncthreads();

    float4 L[5][4];
    // --- issue phase A (tasks 0..31): 20 loads in flight ---
#pragma unroll
    for (int r = 0; r < 5; ++r) {
      int tt = 7 * r + g;
      int t = (tt > 31) ? 31 : tt;
      const float4* r0 = feat4 + a_lds[t];
      L[r][0] = r0[q];
      L[r][1] = r0[9 + q];
      L[r][2] = r0[ROWF4 + q];
      L[r][3] = r0[ROWF4 + 9 + q];
    }
    // --- consume phase A ---
#pragma unroll
    for (int r = 0; r < 5; ++r) {
      int tt = 7 * r + g;
      int t = (tt > 31) ? 31 : tt;
      float4 W4 = w_lds[t];
      float4 v00 = L[r][0], v01 = L[r][1], v10 = L[r][2], v11 = L[r][3];
      float4 a4;
      a4.x = W4.x * v00.x + W4.y * v01.x + W4.z * v10.x + W4.w * v11.x;
      a4.y = W4.x * v00.y + W4.y * v01.y + W4.z * v10.y + W4.w * v11.y;
      a4.z = W4.x * v00.z + W4.y * v01.z + W4.z * v10.z + W4.w * v11.z;
      a4.w = W4.x * v00.w + W4.y * v01.w + W4.z * v10.w + W4.w * v11.w;
      if (tt < 32 && tid < 63) {
        *reinterpret_cast<float4*>(&scratch[t * 36 + 4 * q]) = a4;
      }
    }
    // --- issue phase B (tasks 32..63) BEFORE the phase-A reduce ---
#pragma unroll
    for (int r = 0; r < 5; ++r) {
      int tt = 32 + 7 * r + g;
      int t = (tt > 63) ? 63 : tt;
      const float4* r0 = feat4 + a_lds[t];
      L[r][0] = r0[q];
      L[r][1] = r0[9 + q];
      L[r][2] = r0[ROWF4 + q];
      L[r][3] = r0[ROWF4 + 9 + q];
    }
    // --- phase-A owner reduce + softmax (lanes 0..31) ---
    if (tid < 32) {
      float D[9] = {0.f, 0.f, 0.f, 0.f, 0.f, 0.f, 0.f, 0.f, 0.f};
      const float4* sc = reinterpret_cast<const float4*>(&scratch[tid * 36]);
#pragma unroll
      for (int q2 = 0; q2 < 9; ++q2) {
        float4 a4 = sc[q2];
        float av[4] = {a4.x, a4.y, a4.z, a4.w};
        int ga = q2 / 3;
        int f0 = 4 * (q2 % 3);
#pragma unroll
        for (int j = 0; j < 4; ++j) {
          D[ga]     += fabsf(F[f0 + j]      - av[j]);
          D[3 + ga] += fabsf(F[12 + f0 + j] - av[j]);
          D[6 + ga] += fabsf(F[24 + f0 + j] - av[j]);
        }
      }
      float mn = D[0];
#pragma unroll
      for (int j = 1; j < 9; ++j) mn = fminf(mn, D[j]);
      float xk = -(mn / 12.0f) * 1000.0f;
      float nm = fmaxf(M, xk);
      float scl = expf(M - nm);
      float ek = expf(xk - nm);
      den = den * scl + ek;
      axs = axs * scl + ox * ek;
      ays = ays * scl + oy * ek;
      M = nm;
    }
    // --- consume phase B (DS in-order: these writes follow the reads above) ---
#pragma unroll
    for (int r = 0; r < 5; ++r) {
      int tt = 32 + 7 * r + g;
      int t = (tt > 63) ? 63 : tt;
      float4 W4 = w_lds[t];
      float4 v00 = L[r][0], v01 = L[r][1], v10 = L[r][2], v11 = L[r][3];
      float4 a4;
      a4.x = W4.x * v00.x + W4.y * v01.x + W4.z * v10.x + W4.w * v11.x;
      a4.y = W4.x * v00.y + W4.y * v01.y + W4.z * v10.y + W4.w * v11.y;
      a4.z = W4.x * v00.z + W4.y * v01.z + W4.z * v10.z + W4.w * v11.z;
      a4.w = W4.x * v00.w + W4.y * v01.w + W4.z * v10.w + W4.w * v11.w;
      if (tt < 64 && tid < 63) {
        *reinterpret_cast<float4*>(&scratch[(t - 32) * 36 + 4 * q]) = a4;
      }
    }
    // --- phase-B owner reduce + softmax (lanes 32..63) ---
    if (tid >= 32) {
      float D[9] = {0.f, 0.f, 0.f, 0.f, 0.f, 0.f, 0.f, 0.f, 0.f};
      const float4* sc = reinterpret_cast<const float4*>(&scratch[(tid - 32) * 36]);
#pragma unroll
      for (int q2 = 0; q2 < 9; ++q2) {
        float4 a4 = sc[q2];
        float av[4] = {a4.x, a4.y, a4.z, a4.w};
        int ga = q2 / 3;
        int f0 = 4 * (q2 % 3);
#pragma unroll
        for (int j = 0; j < 4; ++j) {
          D[ga]     += fabsf(F[f0 + j]      - av[j]);
          D[3 + ga] += fabsf(F[12 + f0 + j] - av[j]);
          D[6 + ga] += fabsf(F[24 + f0 + j] - av[j]);
        }
      }
      float mn = D[0];
#pragma unroll
      for (int j = 1; j < 9; ++j) mn = fminf(mn, D[j]);
      float xk = -(mn / 12.0f) * 1000.0f;
      float nm = fmaxf(M, xk);
      float scl = expf(M - nm);
      float ek = expf(xk - nm);
      den = den * scl + ek;
      axs = axs * scl + ox * ek;
      ays = ays * scl + oy * ek;
      M = nm;
    }
  }

  float resx = axs / den;
  float resy = ays / den;
  out[p] = fminf(fmaxf(resx + lx, 0.0f), 511.0f) - lx;
  out[B_ * HW_ + p] = fminf(fmaxf(resy + ly, 0.0f), 511.0f) - ly;
}

// Fallback (no scratch): original channel-major layout, thread-per-pixel.
__global__ __launch_bounds__(256) void eval_kernel_n(const float* __restrict__ feat,
                                                     const float* __restrict__ offx,
                                                     const float* __restrict__ offy,
                                                     float* __restrict__ out) {
  int p = blockIdx.x * 256 + threadIdx.x;
  int ph = p & (HW_ - 1);
  int b = p >> 18;
  float F[C_];
  const float* fb = feat + (size_t)b * C_ * HW_ + ph;
#pragma unroll
  for (int c = 0; c < C_; ++c) F[c] = fb[(size_t)c * HW_];
  float lx = (float)(ph & (W_ - 1));
  float ly = (float)((ph >> 9) & (H_ - 1));
  const float* oxb = offx + (size_t)b * K_ * HW_ + ph;
  const float* oyb = offy + (size_t)b * K_ * HW_ + ph;
  float M = -INFINITY, den = 0.f, ax = 0.f, ay = 0.f;
#pragma unroll 1
  for (int k = 0; k < K_; ++k) {
    float ox = oxb[k * HW_];
    float oy = oyb[k * HW_];
    float rx = fminf(fmaxf(lx + ox, 0.0f), 511.0f);
    float ry = fminf(fmaxf(ly + oy, 0.0f), 511.0f);
    float gx = (rx - 255.5f) / 255.5f;
    float gy = (ry - 255.5f) / 255.5f;
    float px = (gx + 1.0f) * 0.5f * 511.0f;
    float py = (gy + 1.0f) * 0.5f * 511.0f;
    int x0 = (int)floorf(px); x0 = (x0 > 510) ? 510 : x0;
    int y0 = (int)floorf(py); y0 = (y0 > 510) ? 510 : y0;
    float wx = px - (float)x0;
    float wy = py - (float)y0;
    float w00 = (1.0f - wx) * (1.0f - wy);
    float w01 = wx * (1.0f - wy);
    float w10 = (1.0f - wx) * wy;
    float w11 = wx * wy;
    float D[9] = {0.f, 0.f, 0.f, 0.f, 0.f, 0.f, 0.f, 0.f, 0.f};
    const float* pl = feat + (size_t)b * C_ * HW_ + (size_t)y0 * W_ + x0;
#pragma unroll
    for (int c = 0; c < C_; ++c) {
      const float* q0 = pl + (size_t)c * HW_;
      float v00 = q0[0], v01 = q0[1];
      float v10 = q0[W_], v11 = q0[W_ + 1];
      float a = v00 * w00 + v01 * w01 + v10 * w10 + v11 * w11;
      int i = c % 12;
      int ga = c / 12;
      D[ga]     += fabsf(F[i]      - a);
      D[3 + ga] += fabsf(F[12 + i] - a);
      D[6 + ga] += fabsf(F[24 + i] - a);
    }
    float mn = D[0];
#pragma unroll
    for (int j = 1; j < 9; ++j) mn = fminf(mn, D[j]);
    float xk = -(mn / 12.0f) * 1000.0f;
    float nm = fmaxf(M, xk);
    float sc = expf(M - nm);
    float ek = expf(xk - nm);
    den = den * sc + ek;
    ax = ax * sc + ox * ek;
    ay = ay * sc + oy * ek;
    M = nm;
  }
  float resx = ax / den;
  float resy = ay / den;
  out[p] = fminf(fmaxf(resx + lx, 0.0f), 511.0f) - lx;
  out[B_ * HW_ + p] = fminf(fmaxf(resy + ly, 0.0f), 511.0f) - ly;
}

extern "C" void kernel_launch(void* const* d_in, const int* in_sizes, int n_in,
                              void* d_out, int out_size, void* d_ws, size_t ws_size,
                              hipStream_t stream) {
  const float* features = (const float*)d_in[0];
  const float* offset_x = (const float*)d_in[1];
  const float* offset_y = (const float*)d_in[2];
  float* out = (float*)d_out;

  const int npix = B_ * HW_;  // 524288
  const size_t need = (size_t)npix * C_ * sizeof(float);  // 75.5 MB

  if (ws_size >= need) {
    float* featT = (float*)d_ws;
    transpose_kernel<<<B_ * H_ * (W_ / 64), 256, 0, stream>>>(features, featT);
    eval_kernel_cw<<<npix / 64, 64, 0, stream>>>(featT, offset_x, offset_y, out);
  } else {
    eval_kernel_n<<<npix / 256, 256, 0, stream>>>(features, offset_x, offset_y, out);
  }
}